// Round 10
// baseline (10315.121 us; speedup 1.0000x reference)
//
#include <hip/hip_runtime.h>
#include <stdint.h>

// ---------------------------------------------------------------------------
// LSTM_14242111554073  (B=32, S=512, IN=512, H=1024, fp32 in/out)
// R10 = R9 + ONE knob: XCD-LOCAL h-exchange.
//   Scan grid = 256 WGs (1/CU via 82KB LDS => exactly 32 WGs per XCD).
//   Each WG reads HW_REG_XCC_ID and claims a role: XCD0 -> batch group 0,
//   XCD1 -> group 1 (arrival-order atomicAdd gives the col-slice); all other
//   WGs exit. Producers keep sc1 stores (write-through: updates local L2 AND
//   LLC). Consumers use sc0-only loads (L1 bypass, served by the SAME XCD's
//   L2, ~200-300cy instead of loaded-LLC ~2000cy).
//   Safety belts (no new hang modes):
//     * escalation: a wave whose sweep makes no progress for 32 iterations
//       switches its remaining chunk loads to sc0+sc1 (LLC-fresh, correct
//       for any producer placement) -> stale-L2 / wrong-XCD self-heals.
//     * grace-claim: role-less WGs wait ~100us, adopt unclaimed roles
//       (dispatcher pathology degrades to R9-speed instead of deadlock).
// Phase 1 (proven R8): prep + gx_gemm2, bit-identical gx.
// ---------------------------------------------------------------------------

typedef short bf16x8 __attribute__((ext_vector_type(8)));
typedef float f32x4  __attribute__((ext_vector_type(4)));
typedef unsigned int uint4v __attribute__((ext_vector_type(4)));

#define MFMA16(a, b, c) __builtin_amdgcn_mfma_f32_16x16x32_bf16((a), (b), (c), 0, 0, 0)

__device__ __forceinline__ unsigned short f2bf(float f) {
    unsigned int u = __builtin_bit_cast(unsigned int, f);
    u = (u + 0x7FFFu + ((u >> 16) & 1u)) >> 16;   // RNE
    return (unsigned short)u;
}
__device__ __forceinline__ float bf2f(unsigned short h) {
    unsigned int u = ((unsigned int)h) << 16;
    return __builtin_bit_cast(float, u);
}
__device__ __forceinline__ float sigmoidf_(float x) { return 1.0f / (1.0f + __expf(-x)); }
__device__ __forceinline__ float tanhf_(float x)    { return 1.0f - 2.0f / (__expf(2.0f * x) + 1.0f); }

// ---------------------------------------------------------------------------
// Kernel 0: prep. blockIdx < 4096: Xb convert. blockIdx >= 4096: W transpose.
// ---------------------------------------------------------------------------
__global__ void __launch_bounds__(256) prep(
    const float* __restrict__ X,
    const float* __restrict__ Wf, const float* __restrict__ Wi,
    const float* __restrict__ Wo, const float* __restrict__ Wc,
    unsigned short* __restrict__ Xb,     // [16384*512] bf16
    unsigned short* __restrict__ WbT)    // [4096][512] bf16
{
    __shared__ unsigned short T[64][72];
    const int tid = threadIdx.x;
    int bid = blockIdx.x;

    if (bid < 4096) {
        size_t s = ((size_t)bid * 256 + tid) * 8;
        float4 v0 = *(const float4*)(X + s);
        float4 v1 = *(const float4*)(X + s + 4);
        unsigned int p0 = (unsigned int)f2bf(v0.x) | ((unsigned int)f2bf(v0.y) << 16);
        unsigned int p1 = (unsigned int)f2bf(v0.z) | ((unsigned int)f2bf(v0.w) << 16);
        unsigned int p2 = (unsigned int)f2bf(v1.x) | ((unsigned int)f2bf(v1.y) << 16);
        unsigned int p3 = (unsigned int)f2bf(v1.z) | ((unsigned int)f2bf(v1.w) << 16);
        uint4v q; q[0] = p0; q[1] = p1; q[2] = p2; q[3] = p3;
        *(uint4v*)(Xb + s) = q;
        return;
    }

    bid -= 4096;
    const int gate = bid >> 7;
    const int r    = bid & 127;
    const int n0   = (r >> 3) * 64;
    const int k0   = (r & 7) * 64;
    const float* Wg = (gate == 0) ? Wf : (gate == 1) ? Wi : (gate == 2) ? Wo : Wc;

#pragma unroll
    for (int it = 0; it < 4; it++) {
        int s  = tid + it * 256;
        int kr = s >> 4;
        int c4 = s & 15;
        float4 v = *(const float4*)(Wg + (size_t)(k0 + kr) * 1024 + n0 + c4 * 4);
        T[c4 * 4 + 0][kr] = f2bf(v.x);
        T[c4 * 4 + 1][kr] = f2bf(v.y);
        T[c4 * 4 + 2][kr] = f2bf(v.z);
        T[c4 * 4 + 3][kr] = f2bf(v.w);
    }
    __syncthreads();
#pragma unroll
    for (int it = 0; it < 2; it++) {
        int s   = tid + it * 256;
        int nr  = s >> 3;
        int seg = s & 7;
        uint4v q = *(const uint4v*)&T[nr][seg * 8];
        *(uint4v*)(WbT + ((size_t)gate * 1024 + n0 + nr) * 512 + k0 + seg * 8) = q;
    }
}

// ---------------------------------------------------------------------------
// Kernel 1: gx GEMM (bf16 inputs).  C[16384 x 4096] = Xb @ WbT^T, bf16 out.
// ---------------------------------------------------------------------------
__global__ void __launch_bounds__(256) gx_gemm2(
    const unsigned short* __restrict__ Xb,
    const unsigned short* __restrict__ WbT,
    unsigned short* __restrict__ gxOut)
{
    __shared__ unsigned short As[128 * 40];
    __shared__ unsigned short Bs[128 * 40];

    const int tid  = threadIdx.x;
    const int lane = tid & 63;
    const int wid  = tid >> 6;
    const int lr   = lane & 15;
    const int lq   = lane >> 4;

    const int m0 = blockIdx.x * 128;
    const int n0 = blockIdx.y * 128;

    const int mw = (wid & 1) * 64;
    const int nw = (wid >> 1) * 64;

    f32x4 acc[4][4];
#pragma unroll
    for (int i = 0; i < 4; i++)
#pragma unroll
        for (int j = 0; j < 4; j++) acc[i][j] = (f32x4){0.f, 0.f, 0.f, 0.f};

    for (int k0 = 0; k0 < 512; k0 += 32) {
#pragma unroll
        for (int it = 0; it < 2; it++) {
            int s   = tid + it * 256;
            int row = s >> 2;
            int seg = s & 3;
            uint4v va = *(const uint4v*)(Xb + (size_t)(m0 + row) * 512 + k0 + seg * 8);
            *(uint4v*)(As + row * 40 + seg * 8) = va;
            uint4v vb = *(const uint4v*)(WbT + (size_t)(n0 + row) * 512 + k0 + seg * 8);
            *(uint4v*)(Bs + row * 40 + seg * 8) = vb;
        }
        __syncthreads();

        bf16x8 af[4], bfr[4];
#pragma unroll
        for (int tm = 0; tm < 4; tm++)
            af[tm] = *(const bf16x8*)(As + (mw + tm * 16 + lr) * 40 + lq * 8);
#pragma unroll
        for (int tn = 0; tn < 4; tn++)
            bfr[tn] = *(const bf16x8*)(Bs + (nw + tn * 16 + lr) * 40 + lq * 8);
#pragma unroll
        for (int tm = 0; tm < 4; tm++)
#pragma unroll
            for (int tn = 0; tn < 4; tn++)
                acc[tm][tn] = MFMA16(af[tm], bfr[tn], acc[tm][tn]);
        __syncthreads();
    }

#pragma unroll
    for (int tm = 0; tm < 4; tm++)
#pragma unroll
        for (int tn = 0; tn < 4; tn++)
#pragma unroll
            for (int r = 0; r < 4; r++) {
                int row = m0 + mw + tm * 16 + lq * 4 + r;
                int col = n0 + nw + tn * 16 + lr;
                gxOut[(size_t)row * 4096 + col] = f2bf(acc[tm][tn][r]);
            }
}

// ---------------------------------------------------------------------------
// Kernel 2: persistent scan. Grid 256 (32/XCD); 64 claim roles, rest exit.
// ---------------------------------------------------------------------------
#define NWG_GRID 256
#define LDS2_BYTES 82432
#define KSTR 2560
#define CSTR 20

__device__ __forceinline__ void fence_barrier_lgkm() {
    asm volatile("s_waitcnt lgkmcnt(0)" ::: "memory");
    __builtin_amdgcn_sched_barrier(0);
    __builtin_amdgcn_s_barrier();
    __builtin_amdgcn_sched_barrier(0);
    asm volatile("" ::: "memory");
}
__device__ __forceinline__ void fence_barrier_plain() {
    asm volatile("" ::: "memory");
    __builtin_amdgcn_sched_barrier(0);
    __builtin_amdgcn_s_barrier();
    __builtin_amdgcn_sched_barrier(0);
    asm volatile("" ::: "memory");
}

__global__ void __launch_bounds__(512, 1) lstm_scan(
    const float* __restrict__ Whf, const float* __restrict__ Whi,
    const float* __restrict__ Who, const float* __restrict__ Whc,
    const float* __restrict__ Bf,  const float* __restrict__ Bi,
    const float* __restrict__ Bo,  const float* __restrict__ Bc,
    const unsigned short* __restrict__ gx,
    unsigned short* __restrict__ hhist,   // [512][32][1024] bf16, prefilled 0xFF
    unsigned int* __restrict__ claim,     // [8] zeroed role counters
    float* __restrict__ out)
{
    extern __shared__ char lds[];
    float* glds = (float*)lds;            // 81920 B
    float* blds = (float*)(lds + 81920);  //   512 B

    const int tid  = threadIdx.x;
    const int lane = tid & 63;
    const int kq   = tid >> 6;
    const int lr   = lane & 15;
    const int lq   = lane >> 4;

    // ---- role claim: XCD0 -> group 0, XCD1 -> group 1, col-slice by arrival
    if (tid == 0) {
        unsigned int xcc = 0xFFu;
        asm volatile("s_getreg_b32 %0, hwreg(HW_REG_XCC_ID)" : "=s"(xcc));
        int role = -1;
        if (xcc < 2u) {
            unsigned int idx = atomicAdd(&claim[xcc], 1u);
            if (idx < 32u) role = (int)(xcc * 32u + idx);
        }
        if (role < 0) {
            // grace: ~100us, then adopt any unclaimed roles (anti-deadlock;
            // cross-XCD adoption stays correct via sweep escalation)
            for (int i = 0; i < 32; i++) asm volatile("s_sleep 127");
            for (unsigned int g = 0; g < 2u && role < 0; g++) {
                if (__hip_atomic_load(&claim[g], __ATOMIC_RELAXED,
                                      __HIP_MEMORY_SCOPE_AGENT) < 32u) {
                    unsigned int idx = atomicAdd(&claim[g], 1u);
                    if (idx < 32u) role = (int)(g * 32u + idx);
                }
            }
        }
        *(volatile int*)lds = role;
    }
    __syncthreads();
    const int role = *(volatile int*)lds;
    if (role < 0) return;
    const int bg = role >> 5;           // batch group: rows bg*16..+15
    const int cg = role & 31;           // col slice
    const int j0 = cg * 32;
    __syncthreads();                    // role slot re-used as glds below

    if (tid < 128) {
        int g = tid >> 5, jj = tid & 31;
        const float* bp = (g == 0) ? Bf : (g == 1) ? Bi : (g == 2) ? Bo : Bc;
        blds[tid] = bp[j0 + jj];
    }

    bf16x8 bfrag[8][4];
#pragma unroll
    for (int ct = 0; ct < 8; ct++) {
        int c = ct * 16 + lr;
        int g = c >> 5, jj = c & 31;
        const float* wp = (g == 0) ? Whf : (g == 1) ? Whi : (g == 2) ? Who : Whc;
#pragma unroll
        for (int ks = 0; ks < 4; ks++) {
            int kbase = kq * 128 + ks * 32 + lq * 8;
            bf16x8 b;
#pragma unroll
            for (int j = 0; j < 8; j++)
                b[j] = (short)f2bf(wp[(size_t)(kbase + j) * 1024 + j0 + jj]);
            bfrag[ct][ks] = b;
        }
    }

    const int cb = tid >> 5;
    const int cj = tid & 31;
    const int b  = bg * 16 + cb;
    float c_reg = 0.f;

    __syncthreads();

    for (int t = 0; t < 512; t++) {
        const unsigned short* gxr = gx + ((size_t)(b * 512 + t)) * 4096 + j0 + cj;
        float gxv[4];
#pragma unroll
        for (int g = 0; g < 4; g++) gxv[g] = bf2f(gxr[(size_t)g * 1024]);

        if (t > 0) {
            const unsigned short* hsrc = hhist + (size_t)t * 32768;

            f32x4 acc[8];
#pragma unroll
            for (int ct = 0; ct < 8; ct++) acc[ct] = (f32x4){0.f, 0.f, 0.f, 0.f};

            uint4v fa[4];
            unsigned int pend = 0xFu;
            int fruitless = 0;
            bool esc = false;
            while (pend) {
#pragma unroll
                for (int ks = 0; ks < 4; ks++) {
                    if (pend & (1u << ks)) {
                        const unsigned short* p = hsrc + (bg * 16 + lr) * 1024
                                                   + kq * 128 + ks * 32 + lq * 8;
                        if (!esc)
                            asm volatile("global_load_dwordx4 %0, %1, off sc0"
                                         : "=v"(fa[ks]) : "v"(p));
                        else
                            asm volatile("global_load_dwordx4 %0, %1, off sc0 sc1"
                                         : "=v"(fa[ks]) : "v"(p));
                    }
                }
                asm volatile("s_waitcnt vmcnt(0)" ::: "memory");
                __builtin_amdgcn_sched_barrier(0);

                unsigned int np = 0;
#pragma unroll
                for (int ks = 0; ks < 4; ks++) {
                    if (pend & (1u << ks)) {
                        uint4v u = fa[ks];
                        bool dirty = (u[0] == 0xFFFFFFFFu) | (u[1] == 0xFFFFFFFFu)
                                   | (u[2] == 0xFFFFFFFFu) | (u[3] == 0xFFFFFFFFu);
                        if (__any(dirty)) {
                            np |= 1u << ks;
                        } else {
                            bf16x8 a = __builtin_bit_cast(bf16x8, u);
#pragma unroll
                            for (int ct = 0; ct < 8; ct++)
                                acc[ct] = MFMA16(a, bfrag[ct][ks], acc[ct]);
                        }
                    }
                }
                if (np == pend) { if (++fruitless >= 32) esc = true; }
                else fruitless = 0;
                pend = np;
            }

#pragma unroll
            for (int ct = 0; ct < 8; ct++)
                *(f32x4*)(glds + kq * KSTR + (ct * 16 + lr) * CSTR + lq * 4)
                    = acc[ct];
        }
        // barrier B: own ds_writes complete; NO vmem drain
        fence_barrier_lgkm();

        float sg[4];
#pragma unroll
        for (int g = 0; g < 4; g++) {
            float dot = 0.f;
            if (t > 0) {
#pragma unroll
                for (int p = 0; p < 8; p++)
                    dot += glds[p * KSTR + (g * 32 + cj) * CSTR + cb];
            }
            sg[g] = sigmoidf_(dot + gxv[g] + blds[g * 32 + cj]);
        }
        float cn = sg[0] * c_reg + sg[1] * sg[3];
        c_reg = cn;
        float hn = sg[2] * tanhf_(cn);

        if (t < 511) {
            unsigned int hb = (unsigned int)f2bf(hn);
            unsigned int nb = (unsigned int)__shfl_xor((int)hb, 1);
            unsigned int v  = (hb & 0xFFFFu) | (nb << 16);
            unsigned int v2 = (unsigned int)__shfl_xor((int)v, 2);
            unsigned int v4 = (unsigned int)__shfl_xor((int)v, 4);
            unsigned int v6 = (unsigned int)__shfl_xor((int)v2, 4);
            if ((cj & 7) == 0) {
                uint4v q;
                q[0] = v; q[1] = v2; q[2] = v4; q[3] = v6;
                unsigned short* dst = hhist + (size_t)(t + 1) * 32768
                                      + b * 1024 + j0 + cj;
                // sc1: write-through -> updates local L2 (consumers' fast
                // path on this XCD) AND the LLC (escalated readers).
                asm volatile("global_store_dwordx4 %0, %1, off sc1"
                             :: "v"(dst), "v"(q) : "memory");
            }
            out[((size_t)b * 512 + t) * 1024 + j0 + cj] = sg[2];
        } else {
            out[((size_t)b * 512 + t) * 1024 + j0 + cj] = sg[2];
            out[16777216 + b * 1024 + j0 + cj]          = hn;   // ht
            out[16777216 + 32768 + b * 1024 + j0 + cj]  = cn;   // ct
        }
        // barrier D: ds_reads already consumed; stores stay in flight
        fence_barrier_plain();
    }
}

__global__ void ws_diag(float* out, float mb) { out[threadIdx.x] = -mb; }

extern "C" void kernel_launch(void* const* d_in, const int* in_sizes, int n_in,
                              void* d_out, int out_size, void* d_ws, size_t ws_size,
                              hipStream_t stream)
{
    const float* x   = (const float*)d_in[0];
    const float* wxf = (const float*)d_in[1];
    const float* whf = (const float*)d_in[2];
    const float* bhf = (const float*)d_in[3];
    const float* wxi = (const float*)d_in[4];
    const float* whi = (const float*)d_in[5];
    const float* bhi = (const float*)d_in[6];
    const float* wxo = (const float*)d_in[7];
    const float* who = (const float*)d_in[8];
    const float* bho = (const float*)d_in[9];
    const float* wxc = (const float*)d_in[10];
    const float* whc = (const float*)d_in[11];
    const float* bhc = (const float*)d_in[12];
    float* out = (float*)d_out;

    const size_t GX_BYTES = (size_t)16384 * 4096 * 2;    // 134217728
    const size_t HH_BYTES = (size_t)512 * 32 * 1024 * 2; //  33554432
    const size_t CL_BYTES = 256;
    const size_t NEED = GX_BYTES + HH_BYTES + CL_BYTES;

    if (ws_size < NEED) {
        ws_diag<<<dim3(1), dim3(256), 0, stream>>>(out, (float)(ws_size >> 20));
        return;
    }

    unsigned short* gxbuf = (unsigned short*)d_ws;
    unsigned short* hh    = (unsigned short*)((char*)d_ws + GX_BYTES);
    unsigned int*   cnt   = (unsigned int*)((char*)d_ws + GX_BYTES + HH_BYTES);
    unsigned short* Xb  = hh;
    unsigned short* WbT = hh + 8388608;   // +16MB

    (void)hipFuncSetAttribute((const void*)lstm_scan,
                              hipFuncAttributeMaxDynamicSharedMemorySize, LDS2_BYTES);

    prep<<<dim3(4608), dim3(256), 0, stream>>>(x, wxf, wxi, wxo, wxc, Xb, WbT);
    gx_gemm2<<<dim3(128, 32), dim3(256), 0, stream>>>(Xb, WbT, gxbuf);
    hipMemsetAsync(hh, 0xFF, HH_BYTES, stream);
    hipMemsetAsync(cnt, 0, CL_BYTES, stream);
    lstm_scan<<<dim3(NWG_GRID), dim3(512), LDS2_BYTES, stream>>>(
        whf, whi, who, whc, bhf, bhi, bho, bhc, gxbuf, hh, cnt, out);
}